// Round 1
// baseline (1465.189 us; speedup 1.0000x reference)
//
#include <hip/hip_runtime.h>
#include <math.h>

#define N_NODES 50000
#define N_EDGES 800000
#define D 128
#define E_FEAT 16
#define NLAYERS 3
#define BN_EPS 1e-5f
#define INV_SQRT2 0.70710678118654752f

__device__ __forceinline__ float gelu_exact(float v) {
    return 0.5f * v * (1.0f + erff(v * 0.70710678118654752f));
}

// ---------------- message + scatter kernel ----------------
// m = gelu(x[src] + edge_attr@We + be) * ew ; atomicAdd into agg[dst]
#define EPT 16  // edges staged per block iteration

__global__ __launch_bounds__(256) void message_kernel(
    const float* __restrict__ x,
    const int* __restrict__ src,
    const int* __restrict__ dst,
    const float* __restrict__ edge_attr,  // E x 16
    const float* __restrict__ ew,
    const float* __restrict__ We,         // 16 x 128
    const float* __restrict__ be,         // 128
    float* __restrict__ agg)              // N x 128, pre-zeroed
{
    __shared__ float sWe[E_FEAT][D];
    __shared__ float sbe[D];
    __shared__ float sea[EPT * E_FEAT];
    __shared__ int   ssrc[EPT];
    __shared__ int   sdst[EPT];
    __shared__ float sew[EPT];

    const int t = threadIdx.x;
    for (int i = t; i < E_FEAT * D; i += 256) sWe[i / D][i % D] = We[i];
    if (t < D) sbe[t] = be[t];

    const int g = t >> 7;     // 0/1: which 128-thread group
    const int c = t & 127;    // feature dim
    const int n_tiles = N_EDGES / EPT;

    for (int tile = blockIdx.x; tile < n_tiles; tile += gridDim.x) {
        const int e0 = tile * EPT;
        if (t < EPT)            ssrc[t]          = src[e0 + t];
        else if (t < 2 * EPT)   sdst[t - EPT]    = dst[e0 + t - EPT];
        else if (t < 3 * EPT)   sew[t - 2 * EPT] = ew[e0 + t - 2 * EPT];
        sea[t] = edge_attr[(size_t)e0 * E_FEAT + t];  // 256 floats, coalesced
        __syncthreads();

        #pragma unroll 1
        for (int j = 0; j < EPT / 2; ++j) {
            const int le = g * (EPT / 2) + j;
            const int s  = ssrc[le];
            const int dd = sdst[le];
            const float w = sew[le];
            const float* ea = &sea[le * E_FEAT];
            float emb = sbe[c];
            #pragma unroll
            for (int k = 0; k < E_FEAT; ++k) emb += ea[k] * sWe[k][c];
            const float v = x[(size_t)s * D + c] + emb;
            const float m = gelu_exact(v) * w;
            atomicAdd(&agg[(size_t)dd * D + c], m);
        }
        __syncthreads();
    }
}

// ---------------- MLP part 1: T = gelu(((1+eps)*x + agg) @ W1 + b1) ----------------
#define GM 64  // rows per block
#define LDA 132  // padded leading dim (4*r+k bank pattern, float4-aligned)

__global__ __launch_bounds__(256) void mlp1_kernel(
    const float* __restrict__ x,
    const float* __restrict__ agg,
    const float* __restrict__ W,    // 128x128 (this layer)
    const float* __restrict__ b,    // 128
    const float* __restrict__ eps,  // scalar (this layer)
    float* __restrict__ T)
{
    __shared__ float sA[GM][LDA];
    const int t = threadIdx.x;
    const int row0 = blockIdx.x * GM;
    const float e1 = 1.0f + *eps;

    for (int i = t; i < GM * (D / 4); i += 256) {
        const int r  = i / (D / 4);
        const int cc = (i % (D / 4)) * 4;
        const int gr = row0 + r;
        float4 v;
        if (gr < N_NODES) {
            float4 xv = *(const float4*)&x[(size_t)gr * D + cc];
            float4 av = *(const float4*)&agg[(size_t)gr * D + cc];
            v.x = e1 * xv.x + av.x; v.y = e1 * xv.y + av.y;
            v.z = e1 * xv.z + av.z; v.w = e1 * xv.w + av.w;
        } else { v.x = v.y = v.z = v.w = 0.0f; }
        *(float4*)&sA[r][cc] = v;
    }
    __syncthreads();

    const int cg = t & 31;   // 32 col-groups of 4
    const int rg = t >> 5;   // 8 row-groups of 8
    const int c0 = cg * 4;
    const int r0 = rg * 8;
    float acc[8][4];
    #pragma unroll
    for (int r = 0; r < 8; ++r)
        #pragma unroll
        for (int cc = 0; cc < 4; ++cc) acc[r][cc] = 0.0f;

    for (int k = 0; k < D; k += 4) {
        const float4 w0 = *(const float4*)&W[(size_t)(k + 0) * D + c0];
        const float4 w1 = *(const float4*)&W[(size_t)(k + 1) * D + c0];
        const float4 w2 = *(const float4*)&W[(size_t)(k + 2) * D + c0];
        const float4 w3 = *(const float4*)&W[(size_t)(k + 3) * D + c0];
        #pragma unroll
        for (int r = 0; r < 8; ++r) {
            const float4 a = *(const float4*)&sA[r0 + r][k];
            acc[r][0] += a.x * w0.x + a.y * w1.x + a.z * w2.x + a.w * w3.x;
            acc[r][1] += a.x * w0.y + a.y * w1.y + a.z * w2.y + a.w * w3.y;
            acc[r][2] += a.x * w0.z + a.y * w1.z + a.z * w2.z + a.w * w3.z;
            acc[r][3] += a.x * w0.w + a.y * w1.w + a.z * w2.w + a.w * w3.w;
        }
    }

    const float4 bb = *(const float4*)&b[c0];
    #pragma unroll
    for (int r = 0; r < 8; ++r) {
        const int gr = row0 + r0 + r;
        if (gr < N_NODES) {
            float4 o;
            o.x = gelu_exact(acc[r][0] + bb.x);
            o.y = gelu_exact(acc[r][1] + bb.y);
            o.z = gelu_exact(acc[r][2] + bb.z);
            o.w = gelu_exact(acc[r][3] + bb.w);
            *(float4*)&T[(size_t)gr * D + c0] = o;
        }
    }
}

// ---------------- MLP part 2: H = T @ W2 + b2, plus column sum/sumsq ----------------
__global__ __launch_bounds__(256) void mlp2_kernel(
    const float* __restrict__ T,
    const float* __restrict__ W,
    const float* __restrict__ b,
    float* __restrict__ H,
    float* __restrict__ colsum,    // 128, pre-zeroed
    float* __restrict__ colsumsq)  // 128, pre-zeroed
{
    __shared__ float sA[GM][LDA];
    const int t = threadIdx.x;
    const int row0 = blockIdx.x * GM;

    for (int i = t; i < GM * (D / 4); i += 256) {
        const int r  = i / (D / 4);
        const int cc = (i % (D / 4)) * 4;
        const int gr = row0 + r;
        float4 v;
        if (gr < N_NODES) v = *(const float4*)&T[(size_t)gr * D + cc];
        else { v.x = v.y = v.z = v.w = 0.0f; }
        *(float4*)&sA[r][cc] = v;
    }
    __syncthreads();

    const int cg = t & 31;
    const int rg = t >> 5;
    const int c0 = cg * 4;
    const int r0 = rg * 8;
    float acc[8][4];
    #pragma unroll
    for (int r = 0; r < 8; ++r)
        #pragma unroll
        for (int cc = 0; cc < 4; ++cc) acc[r][cc] = 0.0f;

    for (int k = 0; k < D; k += 4) {
        const float4 w0 = *(const float4*)&W[(size_t)(k + 0) * D + c0];
        const float4 w1 = *(const float4*)&W[(size_t)(k + 1) * D + c0];
        const float4 w2 = *(const float4*)&W[(size_t)(k + 2) * D + c0];
        const float4 w3 = *(const float4*)&W[(size_t)(k + 3) * D + c0];
        #pragma unroll
        for (int r = 0; r < 8; ++r) {
            const float4 a = *(const float4*)&sA[r0 + r][k];
            acc[r][0] += a.x * w0.x + a.y * w1.x + a.z * w2.x + a.w * w3.x;
            acc[r][1] += a.x * w0.y + a.y * w1.y + a.z * w2.y + a.w * w3.y;
            acc[r][2] += a.x * w0.z + a.y * w1.z + a.z * w2.z + a.w * w3.z;
            acc[r][3] += a.x * w0.w + a.y * w1.w + a.z * w2.w + a.w * w3.w;
        }
    }

    const float4 bb = *(const float4*)&b[c0];
    float s[4] = {0.f, 0.f, 0.f, 0.f};
    float q[4] = {0.f, 0.f, 0.f, 0.f};
    #pragma unroll
    for (int r = 0; r < 8; ++r) {
        const int gr = row0 + r0 + r;
        if (gr < N_NODES) {
            float4 o;
            o.x = acc[r][0] + bb.x; o.y = acc[r][1] + bb.y;
            o.z = acc[r][2] + bb.z; o.w = acc[r][3] + bb.w;
            *(float4*)&H[(size_t)gr * D + c0] = o;
            s[0] += o.x; s[1] += o.y; s[2] += o.z; s[3] += o.w;
            q[0] += o.x * o.x; q[1] += o.y * o.y; q[2] += o.z * o.z; q[3] += o.w * o.w;
        }
    }

    __syncthreads();  // done with sA as A-tile
    #pragma unroll
    for (int cc = 0; cc < 4; ++cc) {
        sA[rg][c0 + cc]     = s[cc];
        sA[8 + rg][c0 + cc] = q[cc];
    }
    __syncthreads();
    if (t < D) {
        float ss = 0.f, qq = 0.f;
        #pragma unroll
        for (int gg = 0; gg < 8; ++gg) { ss += sA[gg][t]; qq += sA[8 + gg][t]; }
        atomicAdd(&colsum[t], ss);
        atomicAdd(&colsumsq[t], qq);
    }
}

// ---------------- BN apply + gelu + residual (in-place on x) ----------------
__global__ __launch_bounds__(256) void bn_apply_kernel(
    const float* __restrict__ H,
    const float* __restrict__ colsum,
    const float* __restrict__ colsumsq,
    const float* __restrict__ gamma,
    const float* __restrict__ beta,
    float* __restrict__ x)
{
    const int idx = blockIdx.x * 256 + threadIdx.x;  // float4 index, total N*D/4
    const int c0 = (idx & 31) * 4;
    const float invN = 1.0f / (float)N_NODES;

    const float4 s  = *(const float4*)&colsum[c0];
    const float4 q  = *(const float4*)&colsumsq[c0];
    const float4 g  = *(const float4*)&gamma[c0];
    const float4 bt = *(const float4*)&beta[c0];
    const float4 h  = *(const float4*)&H[(size_t)idx * 4];
    const float4 xv = *(const float4*)&x[(size_t)idx * 4];

    float4 o;
    {
        float mu = s.x * invN, var = q.x * invN - mu * mu;
        float hn = (h.x - mu) * rsqrtf(var + BN_EPS) * g.x + bt.x;
        o.x = (xv.x + gelu_exact(hn)) * INV_SQRT2;
    }
    {
        float mu = s.y * invN, var = q.y * invN - mu * mu;
        float hn = (h.y - mu) * rsqrtf(var + BN_EPS) * g.y + bt.y;
        o.y = (xv.y + gelu_exact(hn)) * INV_SQRT2;
    }
    {
        float mu = s.z * invN, var = q.z * invN - mu * mu;
        float hn = (h.z - mu) * rsqrtf(var + BN_EPS) * g.z + bt.z;
        o.z = (xv.z + gelu_exact(hn)) * INV_SQRT2;
    }
    {
        float mu = s.w * invN, var = q.w * invN - mu * mu;
        float hn = (h.w - mu) * rsqrtf(var + BN_EPS) * g.w + bt.w;
        o.w = (xv.w + gelu_exact(hn)) * INV_SQRT2;
    }
    *(float4*)&x[(size_t)idx * 4] = o;
}

extern "C" void kernel_launch(void* const* d_in, const int* in_sizes, int n_in,
                              void* d_out, int out_size, void* d_ws, size_t ws_size,
                              hipStream_t stream) {
    const float* x_in  = (const float*)d_in[0];
    const int*   ei    = (const int*)d_in[1];   // int64 in ref; harness stages integers as int32
    const float* ea    = (const float*)d_in[2];
    const float* ew    = (const float*)d_in[3];
    const float* We    = (const float*)d_in[4];
    const float* be    = (const float*)d_in[5];
    const float* W1    = (const float*)d_in[6];
    const float* b1    = (const float*)d_in[7];
    const float* W2    = (const float*)d_in[8];
    const float* b2    = (const float*)d_in[9];
    const float* eps   = (const float*)d_in[10];
    const float* gamma = (const float*)d_in[11];
    const float* beta  = (const float*)d_in[12];

    const int* src = ei;
    const int* dst = ei + N_EDGES;

    float* xcur = (float*)d_out;

    // workspace layout: [agg N*D][colsum 128][colsumsq 128][T N*D][H N*D]
    float* agg      = (float*)d_ws;
    float* colsum   = agg + (size_t)N_NODES * D;
    float* colsumsq = colsum + D;
    float* T        = colsumsq + D;
    float* H        = T + (size_t)N_NODES * D;

    hipMemcpyAsync(xcur, x_in, sizeof(float) * (size_t)N_NODES * D,
                   hipMemcpyDeviceToDevice, stream);

    const int mlp_blocks = (N_NODES + GM - 1) / GM;       // 782
    const int bn_blocks  = (N_NODES * D / 4) / 256;       // 6250 exact

    for (int i = 0; i < NLAYERS; ++i) {
        // zero agg + colsum + colsumsq (contiguous)
        hipMemsetAsync(agg, 0, sizeof(float) * ((size_t)N_NODES * D + 2 * D), stream);
        message_kernel<<<2048, 256, 0, stream>>>(xcur, src, dst, ea, ew, We, be, agg);
        mlp1_kernel<<<mlp_blocks, 256, 0, stream>>>(xcur, agg,
                                                    W1 + (size_t)i * D * D, b1 + (size_t)i * D,
                                                    eps + i, T);
        mlp2_kernel<<<mlp_blocks, 256, 0, stream>>>(T, W2 + (size_t)i * D * D,
                                                    b2 + (size_t)i * D, H, colsum, colsumsq);
        bn_apply_kernel<<<bn_blocks, 256, 0, stream>>>(H, colsum, colsumsq,
                                                       gamma + (size_t)i * D, beta + (size_t)i * D,
                                                       xcur);
    }
}

// Round 2
// 1123.122 us; speedup vs baseline: 1.3046x; 1.3046x over previous
//
#include <hip/hip_runtime.h>
#include <math.h>

#define N_NODES 50000
#define N_EDGES 800000
#define D 128
#define E_FEAT 16
#define NLAYERS 3
#define BN_EPS 1e-5f
#define INV_SQRT2 0.70710678118654752f

__device__ __forceinline__ float gelu_exact(float v) {
    return 0.5f * v * (1.0f + erff(v * 0.70710678118654752f));
}

__device__ __forceinline__ float lane_bcast_f(float v, int l) {
    return __uint_as_float(__builtin_amdgcn_readlane(__float_as_uint(v), l));
}

// ---------------- CSR build ----------------
__global__ __launch_bounds__(256) void count_kernel(const int* __restrict__ dst,
                                                    int* __restrict__ counts) {
    int e = blockIdx.x * 256 + threadIdx.x;
    if (e < N_EDGES) atomicAdd(&counts[dst[e]], 1);
}

__global__ __launch_bounds__(1024) void scan_kernel(const int* __restrict__ counts,
                                                    int* __restrict__ offsets,
                                                    int* __restrict__ cursor) {
    __shared__ int wsum[16];
    __shared__ int wexcl[16];
    __shared__ int s_run;
    const int t = threadIdx.x, lane = t & 63, wid = t >> 6;
    if (t == 0) s_run = 0;
    __syncthreads();
    for (int base = 0; base < N_NODES; base += 1024) {
        const int idx = base + t;
        int v = (idx < N_NODES) ? counts[idx] : 0;
        int incl = v;
        #pragma unroll
        for (int off = 1; off < 64; off <<= 1) {
            int u = __shfl_up(incl, off, 64);
            if (lane >= off) incl += u;
        }
        if (lane == 63) wsum[wid] = incl;
        __syncthreads();
        if (wid == 0) {
            int wv = (lane < 16) ? wsum[lane] : 0;
            int winc = wv;
            #pragma unroll
            for (int off = 1; off < 16; off <<= 1) {
                int u = __shfl_up(winc, off, 64);
                if (lane >= off) winc += u;
            }
            if (lane < 16) wexcl[lane] = winc - wv;
        }
        __syncthreads();
        const int run = s_run;
        const int excl = run + wexcl[wid] + (incl - v);
        if (idx < N_NODES) { offsets[idx] = excl; cursor[idx] = excl; }
        __syncthreads();
        if (t == 1023) s_run = run + wexcl[15] + wsum[15];
        __syncthreads();
    }
    if (threadIdx.x == 0) offsets[N_NODES] = s_run;
}

__global__ __launch_bounds__(256) void scatter_kernel(const int* __restrict__ dst,
                                                      int* __restrict__ cursor,
                                                      int* __restrict__ sorted_eid) {
    int e = blockIdx.x * 256 + threadIdx.x;
    if (e < N_EDGES) {
        int p = atomicAdd(&cursor[dst[e]], 1);
        sorted_eid[p] = e;
    }
}

// ---------------- aggregation: one wave per dst node, no atomics ----------------
// pre[n] = (1+eps)*x[n] + sum_{e: dst=n} gelu(x[src_e] + ea_e@We + be) * ew_e
__global__ __launch_bounds__(256) void aggregate_kernel(
    const float* __restrict__ x,
    const int* __restrict__ src,
    const float* __restrict__ edge_attr,   // E x 16
    const float* __restrict__ ew,
    const int* __restrict__ offsets,
    const int* __restrict__ sorted_eid,
    const float* __restrict__ We,          // 16 x 128
    const float* __restrict__ be,          // 128
    const float* __restrict__ eps_p,
    float* __restrict__ pre)               // N x 128
{
    const int t = threadIdx.x;
    const int lane = t & 63;
    const int node = blockIdx.x * 4 + (t >> 6);   // 12500 blocks * 4 waves = 50000 exact
    const int c0 = lane * 2;                      // this lane owns features c0, c0+1

    // We columns for this lane's two features, in registers (32 VGPRs)
    float2 wreg[E_FEAT];
    #pragma unroll
    for (int k = 0; k < E_FEAT; ++k)
        wreg[k] = *(const float2*)&We[k * D + c0];
    const float2 bev = *(const float2*)&be[c0];
    const float e1 = 1.0f + *eps_p;

    const int start = __builtin_amdgcn_readfirstlane(offsets[node]);
    const int end   = __builtin_amdgcn_readfirstlane(offsets[node + 1]);

    float a0 = 0.0f, a1 = 0.0f;
    for (int p = start; p < end; ++p) {
        const int eid = __builtin_amdgcn_readfirstlane(sorted_eid[p]);
        const int s   = __builtin_amdgcn_readfirstlane(src[eid]);
        const float w = ew[eid];
        const float eav = edge_attr[(size_t)eid * E_FEAT + (lane & 15)];
        float m0 = bev.x, m1 = bev.y;
        #pragma unroll
        for (int k = 0; k < E_FEAT; ++k) {
            const float eak = lane_bcast_f(eav, k);
            m0 += eak * wreg[k].x;
            m1 += eak * wreg[k].y;
        }
        const float2 xv = *(const float2*)&x[(size_t)s * D + c0];
        a0 += gelu_exact(xv.x + m0) * w;
        a1 += gelu_exact(xv.y + m1) * w;
    }
    const float2 xn = *(const float2*)&x[(size_t)node * D + c0];
    float2 o;
    o.x = e1 * xn.x + a0;
    o.y = e1 * xn.y + a1;
    *(float2*)&pre[(size_t)node * D + c0] = o;
}

// ---------------- MLP part 1: T = gelu(pre @ W1 + b1) ----------------
#define GM 64
#define LDA 132

__global__ __launch_bounds__(256) void mlp1_kernel(
    const float* __restrict__ pre,
    const float* __restrict__ W,
    const float* __restrict__ b,
    float* __restrict__ T)
{
    __shared__ float sA[GM][LDA];
    const int t = threadIdx.x;
    const int row0 = blockIdx.x * GM;

    for (int i = t; i < GM * (D / 4); i += 256) {
        const int r  = i / (D / 4);
        const int cc = (i % (D / 4)) * 4;
        const int gr = row0 + r;
        float4 v;
        if (gr < N_NODES) v = *(const float4*)&pre[(size_t)gr * D + cc];
        else { v.x = v.y = v.z = v.w = 0.0f; }
        *(float4*)&sA[r][cc] = v;
    }
    __syncthreads();

    const int cg = t & 31;
    const int rg = t >> 5;
    const int c0 = cg * 4;
    const int r0 = rg * 8;
    float acc[8][4];
    #pragma unroll
    for (int r = 0; r < 8; ++r)
        #pragma unroll
        for (int cc = 0; cc < 4; ++cc) acc[r][cc] = 0.0f;

    for (int k = 0; k < D; k += 4) {
        const float4 w0 = *(const float4*)&W[(size_t)(k + 0) * D + c0];
        const float4 w1 = *(const float4*)&W[(size_t)(k + 1) * D + c0];
        const float4 w2 = *(const float4*)&W[(size_t)(k + 2) * D + c0];
        const float4 w3 = *(const float4*)&W[(size_t)(k + 3) * D + c0];
        #pragma unroll
        for (int r = 0; r < 8; ++r) {
            const float4 a = *(const float4*)&sA[r0 + r][k];
            acc[r][0] += a.x * w0.x + a.y * w1.x + a.z * w2.x + a.w * w3.x;
            acc[r][1] += a.x * w0.y + a.y * w1.y + a.z * w2.y + a.w * w3.y;
            acc[r][2] += a.x * w0.z + a.y * w1.z + a.z * w2.z + a.w * w3.z;
            acc[r][3] += a.x * w0.w + a.y * w1.w + a.z * w2.w + a.w * w3.w;
        }
    }

    const float4 bb = *(const float4*)&b[c0];
    #pragma unroll
    for (int r = 0; r < 8; ++r) {
        const int gr = row0 + r0 + r;
        if (gr < N_NODES) {
            float4 o;
            o.x = gelu_exact(acc[r][0] + bb.x);
            o.y = gelu_exact(acc[r][1] + bb.y);
            o.z = gelu_exact(acc[r][2] + bb.z);
            o.w = gelu_exact(acc[r][3] + bb.w);
            *(float4*)&T[(size_t)gr * D + c0] = o;
        }
    }
}

// ---------------- MLP part 2: H = T @ W2 + b2, plus column sum/sumsq ----------------
__global__ __launch_bounds__(256) void mlp2_kernel(
    const float* __restrict__ T,
    const float* __restrict__ W,
    const float* __restrict__ b,
    float* __restrict__ H,
    float* __restrict__ colsum,
    float* __restrict__ colsumsq)
{
    __shared__ float sA[GM][LDA];
    const int t = threadIdx.x;
    const int row0 = blockIdx.x * GM;

    for (int i = t; i < GM * (D / 4); i += 256) {
        const int r  = i / (D / 4);
        const int cc = (i % (D / 4)) * 4;
        const int gr = row0 + r;
        float4 v;
        if (gr < N_NODES) v = *(const float4*)&T[(size_t)gr * D + cc];
        else { v.x = v.y = v.z = v.w = 0.0f; }
        *(float4*)&sA[r][cc] = v;
    }
    __syncthreads();

    const int cg = t & 31;
    const int rg = t >> 5;
    const int c0 = cg * 4;
    const int r0 = rg * 8;
    float acc[8][4];
    #pragma unroll
    for (int r = 0; r < 8; ++r)
        #pragma unroll
        for (int cc = 0; cc < 4; ++cc) acc[r][cc] = 0.0f;

    for (int k = 0; k < D; k += 4) {
        const float4 w0 = *(const float4*)&W[(size_t)(k + 0) * D + c0];
        const float4 w1 = *(const float4*)&W[(size_t)(k + 1) * D + c0];
        const float4 w2 = *(const float4*)&W[(size_t)(k + 2) * D + c0];
        const float4 w3 = *(const float4*)&W[(size_t)(k + 3) * D + c0];
        #pragma unroll
        for (int r = 0; r < 8; ++r) {
            const float4 a = *(const float4*)&sA[r0 + r][k];
            acc[r][0] += a.x * w0.x + a.y * w1.x + a.z * w2.x + a.w * w3.x;
            acc[r][1] += a.x * w0.y + a.y * w1.y + a.z * w2.y + a.w * w3.y;
            acc[r][2] += a.x * w0.z + a.y * w1.z + a.z * w2.z + a.w * w3.z;
            acc[r][3] += a.x * w0.w + a.y * w1.w + a.z * w2.w + a.w * w3.w;
        }
    }

    const float4 bb = *(const float4*)&b[c0];
    float s[4] = {0.f, 0.f, 0.f, 0.f};
    float q[4] = {0.f, 0.f, 0.f, 0.f};
    #pragma unroll
    for (int r = 0; r < 8; ++r) {
        const int gr = row0 + r0 + r;
        if (gr < N_NODES) {
            float4 o;
            o.x = acc[r][0] + bb.x; o.y = acc[r][1] + bb.y;
            o.z = acc[r][2] + bb.z; o.w = acc[r][3] + bb.w;
            *(float4*)&H[(size_t)gr * D + c0] = o;
            s[0] += o.x; s[1] += o.y; s[2] += o.z; s[3] += o.w;
            q[0] += o.x * o.x; q[1] += o.y * o.y; q[2] += o.z * o.z; q[3] += o.w * o.w;
        }
    }

    __syncthreads();
    #pragma unroll
    for (int cc = 0; cc < 4; ++cc) {
        sA[rg][c0 + cc]     = s[cc];
        sA[8 + rg][c0 + cc] = q[cc];
    }
    __syncthreads();
    if (t < D) {
        float ss = 0.f, qq = 0.f;
        #pragma unroll
        for (int gg = 0; gg < 8; ++gg) { ss += sA[gg][t]; qq += sA[8 + gg][t]; }
        atomicAdd(&colsum[t], ss);
        atomicAdd(&colsumsq[t], qq);
    }
}

// ---------------- BN apply + gelu + residual ----------------
__global__ __launch_bounds__(256) void bn_apply_kernel(
    const float* __restrict__ H,
    const float* __restrict__ colsum,
    const float* __restrict__ colsumsq,
    const float* __restrict__ gamma,
    const float* __restrict__ beta,
    const float* __restrict__ x_in,
    float* __restrict__ x_out)
{
    const int idx = blockIdx.x * 256 + threadIdx.x;
    const int c0 = (idx & 31) * 4;
    const float invN = 1.0f / (float)N_NODES;

    const float4 s  = *(const float4*)&colsum[c0];
    const float4 q  = *(const float4*)&colsumsq[c0];
    const float4 g  = *(const float4*)&gamma[c0];
    const float4 bt = *(const float4*)&beta[c0];
    const float4 h  = *(const float4*)&H[(size_t)idx * 4];
    const float4 xv = *(const float4*)&x_in[(size_t)idx * 4];

    float4 o;
    {
        float mu = s.x * invN, var = q.x * invN - mu * mu;
        float hn = (h.x - mu) * rsqrtf(var + BN_EPS) * g.x + bt.x;
        o.x = (xv.x + gelu_exact(hn)) * INV_SQRT2;
    }
    {
        float mu = s.y * invN, var = q.y * invN - mu * mu;
        float hn = (h.y - mu) * rsqrtf(var + BN_EPS) * g.y + bt.y;
        o.y = (xv.y + gelu_exact(hn)) * INV_SQRT2;
    }
    {
        float mu = s.z * invN, var = q.z * invN - mu * mu;
        float hn = (h.z - mu) * rsqrtf(var + BN_EPS) * g.z + bt.z;
        o.z = (xv.z + gelu_exact(hn)) * INV_SQRT2;
    }
    {
        float mu = s.w * invN, var = q.w * invN - mu * mu;
        float hn = (h.w - mu) * rsqrtf(var + BN_EPS) * g.w + bt.w;
        o.w = (xv.w + gelu_exact(hn)) * INV_SQRT2;
    }
    *(float4*)&x_out[(size_t)idx * 4] = o;
}

extern "C" void kernel_launch(void* const* d_in, const int* in_sizes, int n_in,
                              void* d_out, int out_size, void* d_ws, size_t ws_size,
                              hipStream_t stream) {
    const float* x_in  = (const float*)d_in[0];
    const int*   ei    = (const int*)d_in[1];
    const float* ea    = (const float*)d_in[2];
    const float* ew    = (const float*)d_in[3];
    const float* We    = (const float*)d_in[4];
    const float* be    = (const float*)d_in[5];
    const float* W1    = (const float*)d_in[6];
    const float* b1    = (const float*)d_in[7];
    const float* W2    = (const float*)d_in[8];
    const float* b2    = (const float*)d_in[9];
    const float* eps   = (const float*)d_in[10];
    const float* gamma = (const float*)d_in[11];
    const float* beta  = (const float*)d_in[12];

    const int* src = ei;
    const int* dst = ei + N_EDGES;

    float* xcur = (float*)d_out;

    // workspace layout (floats/ints):
    // [counts 50000][cursor 50000][offsets 50001(+pad)][sorted_eid 800000]
    // [colsum 128][colsumsq 128][pre N*D (aliased by H)][T N*D]
    int* counts      = (int*)d_ws;
    int* cursor      = counts + N_NODES;
    int* offsets     = cursor + N_NODES;
    int* sorted_eid  = offsets + N_NODES + 4;  // small pad for alignment
    float* colsum    = (float*)(sorted_eid + N_EDGES);
    float* colsumsq  = colsum + D;
    float* pre       = colsumsq + D;           // also used as H
    float* T         = pre + (size_t)N_NODES * D;
    float* H         = pre;                    // alias: pre dead after mlp1

    // ---- CSR build (once per call) ----
    hipMemsetAsync(counts, 0, sizeof(int) * N_NODES, stream);
    count_kernel<<<(N_EDGES + 255) / 256, 256, 0, stream>>>(dst, counts);
    scan_kernel<<<1, 1024, 0, stream>>>(counts, offsets, cursor);
    scatter_kernel<<<(N_EDGES + 255) / 256, 256, 0, stream>>>(dst, cursor, sorted_eid);

    const int mlp_blocks = (N_NODES + GM - 1) / GM;   // 782
    const int bn_blocks  = (N_NODES * D / 4) / 256;   // 6250 exact
    const int agg_blocks = N_NODES / 4;               // 12500 exact

    for (int i = 0; i < NLAYERS; ++i) {
        const float* xl = (i == 0) ? x_in : xcur;
        aggregate_kernel<<<agg_blocks, 256, 0, stream>>>(
            xl, src, ea, ew, offsets, sorted_eid, We, be, eps + i, pre);
        mlp1_kernel<<<mlp_blocks, 256, 0, stream>>>(
            pre, W1 + (size_t)i * D * D, b1 + (size_t)i * D, T);
        hipMemsetAsync(colsum, 0, sizeof(float) * 2 * D, stream);
        mlp2_kernel<<<mlp_blocks, 256, 0, stream>>>(
            T, W2 + (size_t)i * D * D, b2 + (size_t)i * D, H, colsum, colsumsq);
        bn_apply_kernel<<<bn_blocks, 256, 0, stream>>>(
            H, colsum, colsumsq, gamma + (size_t)i * D, beta + (size_t)i * D,
            xl, xcur);
    }
}

// Round 3
// 926.960 us; speedup vs baseline: 1.5806x; 1.2116x over previous
//
#include <hip/hip_runtime.h>
#include <math.h>

#define N_NODES 50000
#define N_EDGES 800000
#define D 128
#define E_FEAT 16
#define NLAYERS 3
#define BN_EPS 1e-5f
#define INV_SQRT2 0.70710678118654752f

// Branchless erf (Abramowitz-Stegun 7.1.26, |err| <= 1.5e-7) via hw rcp/exp2.
__device__ __forceinline__ float gelu_fast(float v) {
    const float u = v * INV_SQRT2;
    const float a = __builtin_fabsf(u);
    const float t = __builtin_amdgcn_rcpf(__builtin_fmaf(0.3275911f, a, 1.0f));
    float p = __builtin_fmaf(1.061405429f, t, -1.453152027f);
    p = __builtin_fmaf(p, t, 1.421413741f);
    p = __builtin_fmaf(p, t, -0.284496736f);
    p = __builtin_fmaf(p, t, 0.254829592f);
    p = p * t;
    const float e = __builtin_amdgcn_exp2f(-1.4426950408889634f * a * a);
    const float erf_a = __builtin_fmaf(-p, e, 1.0f);
    const float erf_u = __builtin_copysignf(erf_a, u);
    return 0.5f * v * (1.0f + erf_u);
}

// ---------------- CSR build ----------------
__global__ __launch_bounds__(256) void count_kernel(const int* __restrict__ dst,
                                                    int* __restrict__ counts) {
    int e = blockIdx.x * 256 + threadIdx.x;
    if (e < N_EDGES) atomicAdd(&counts[dst[e]], 1);
}

// scan1: per-block (256 elems) exclusive scan, block sums to bsum
__global__ __launch_bounds__(256) void scan1_kernel(const int* __restrict__ counts,
                                                    int* __restrict__ offsets,
                                                    int* __restrict__ bsum) {
    __shared__ int wsum[4];
    __shared__ int wexcl[4];
    const int t = threadIdx.x, lane = t & 63, wid = t >> 6;
    const int idx = blockIdx.x * 256 + t;
    int v = (idx < N_NODES) ? counts[idx] : 0;
    int incl = v;
    #pragma unroll
    for (int off = 1; off < 64; off <<= 1) {
        int u = __shfl_up(incl, off, 64);
        if (lane >= off) incl += u;
    }
    if (lane == 63) wsum[wid] = incl;
    __syncthreads();
    if (t == 0) {
        int r = 0;
        #pragma unroll
        for (int g = 0; g < 4; ++g) { wexcl[g] = r; r += wsum[g]; }
        bsum[blockIdx.x] = r;
    }
    __syncthreads();
    if (idx < N_NODES) offsets[idx] = wexcl[wid] + (incl - v);
}

// scan2: single block scans 196 block sums -> bbase (exclusive); writes grand total
#define NSCAN_BLOCKS 196
__global__ __launch_bounds__(256) void scan2_kernel(const int* __restrict__ bsum,
                                                    int* __restrict__ bbase,
                                                    int* __restrict__ offsets) {
    __shared__ int wsum[4];
    __shared__ int wexcl[4];
    const int t = threadIdx.x, lane = t & 63, wid = t >> 6;
    int v = (t < NSCAN_BLOCKS) ? bsum[t] : 0;
    int incl = v;
    #pragma unroll
    for (int off = 1; off < 64; off <<= 1) {
        int u = __shfl_up(incl, off, 64);
        if (lane >= off) incl += u;
    }
    if (lane == 63) wsum[wid] = incl;
    __syncthreads();
    if (t == 0) {
        int r = 0;
        #pragma unroll
        for (int g = 0; g < 4; ++g) { wexcl[g] = r; r += wsum[g]; }
        offsets[N_NODES] = r;   // grand total (= N_EDGES)
    }
    __syncthreads();
    if (t < NSCAN_BLOCKS) bbase[t] = wexcl[wid] + (incl - v);
}

// scan3: add block base, fill cursor
__global__ __launch_bounds__(256) void scan3_kernel(int* __restrict__ offsets,
                                                    const int* __restrict__ bbase,
                                                    int* __restrict__ cursor) {
    const int idx = blockIdx.x * 256 + threadIdx.x;
    if (idx < N_NODES) {
        const int o = offsets[idx] + bbase[blockIdx.x];
        offsets[idx] = o;
        cursor[idx] = o;
    }
}

__global__ __launch_bounds__(256) void scatter_kernel(const int* __restrict__ dst,
                                                      int* __restrict__ cursor,
                                                      int* __restrict__ sorted_eid) {
    int e = blockIdx.x * 256 + threadIdx.x;
    if (e < N_EDGES) {
        int p = atomicAdd(&cursor[dst[e]], 1);
        sorted_eid[p] = e;
    }
}

// ---------------- aggregation: one wave per dst node ----------------
// pre[n] = (1+eps)*x[n] + sum_{e: dst=n} gelu(x[src_e] + ea_e@We + be) * ew_e
__global__ __launch_bounds__(256) void aggregate_kernel(
    const float* __restrict__ x,
    const int* __restrict__ src,
    const float* __restrict__ edge_attr,   // E x 16
    const float* __restrict__ ew,
    const int* __restrict__ offsets,
    const int* __restrict__ sorted_eid,
    const float* __restrict__ We,          // 16 x 128
    const float* __restrict__ be,          // 128
    const float* __restrict__ eps_p,
    float* __restrict__ pre)               // N x 128
{
    const int t = threadIdx.x;
    const int lane = t & 63;
    const int node = blockIdx.x * 4 + (t >> 6);   // 12500 blocks * 4 waves
    const int c0 = lane * 2;

    float2 wreg[E_FEAT];
    #pragma unroll
    for (int k = 0; k < E_FEAT; ++k)
        wreg[k] = *(const float2*)&We[k * D + c0];
    const float2 bev = *(const float2*)&be[c0];
    const float e1 = 1.0f + *eps_p;

    const int start = __builtin_amdgcn_readfirstlane(offsets[node]);
    const int end   = __builtin_amdgcn_readfirstlane(offsets[node + 1]);

    float a0 = 0.0f, a1 = 0.0f;
    for (int p = start; p < end; ++p) {
        const int eid = __builtin_amdgcn_readfirstlane(sorted_eid[p]);
        const int s   = __builtin_amdgcn_readfirstlane(src[eid]);
        const float w = ew[eid];                         // uniform -> scalar load
        const float* __restrict__ ea = edge_attr + (size_t)eid * E_FEAT;
        float m0 = bev.x, m1 = bev.y;
        #pragma unroll
        for (int k = 0; k < E_FEAT; ++k) {
            const float eak = ea[k];                     // uniform -> scalar load
            m0 = __builtin_fmaf(eak, wreg[k].x, m0);
            m1 = __builtin_fmaf(eak, wreg[k].y, m1);
        }
        const float2 xv = *(const float2*)&x[(size_t)s * D + c0];
        a0 = __builtin_fmaf(gelu_fast(xv.x + m0), w, a0);
        a1 = __builtin_fmaf(gelu_fast(xv.y + m1), w, a1);
    }
    const float2 xn = *(const float2*)&x[(size_t)node * D + c0];
    float2 o;
    o.x = e1 * xn.x + a0;
    o.y = e1 * xn.y + a1;
    *(float2*)&pre[(size_t)node * D + c0] = o;
}

// ---------------- fused MLP: H = gelu(pre@W1+b1)@W2+b2, plus col stats ----------------
#define GM 64
#define LDA 132

__global__ __launch_bounds__(256) void mlp_fused_kernel(
    const float* __restrict__ pre,
    const float* __restrict__ W1,
    const float* __restrict__ b1,
    const float* __restrict__ W2,
    const float* __restrict__ b2,
    float* __restrict__ H,
    float* __restrict__ colsum,
    float* __restrict__ colsumsq)
{
    __shared__ float sA[GM][LDA];
    const int t = threadIdx.x;
    const int row0 = blockIdx.x * GM;

    // phase 1: load pre tile
    for (int i = t; i < GM * (D / 4); i += 256) {
        const int r  = i / (D / 4);
        const int cc = (i % (D / 4)) * 4;
        const int gr = row0 + r;
        float4 v;
        if (gr < N_NODES) v = *(const float4*)&pre[(size_t)gr * D + cc];
        else { v.x = v.y = v.z = v.w = 0.0f; }
        *(float4*)&sA[r][cc] = v;
    }
    __syncthreads();

    const int cg = t & 31;
    const int rg = t >> 5;
    const int c0 = cg * 4;
    const int r0 = rg * 8;
    float acc[8][4];

    // ---- GEMM 1 ----
    #pragma unroll
    for (int r = 0; r < 8; ++r)
        #pragma unroll
        for (int cc = 0; cc < 4; ++cc) acc[r][cc] = 0.0f;

    for (int k = 0; k < D; k += 4) {
        const float4 w0 = *(const float4*)&W1[(size_t)(k + 0) * D + c0];
        const float4 w1 = *(const float4*)&W1[(size_t)(k + 1) * D + c0];
        const float4 w2 = *(const float4*)&W1[(size_t)(k + 2) * D + c0];
        const float4 w3 = *(const float4*)&W1[(size_t)(k + 3) * D + c0];
        #pragma unroll
        for (int r = 0; r < 8; ++r) {
            const float4 a = *(const float4*)&sA[r0 + r][k];
            acc[r][0] += a.x * w0.x + a.y * w1.x + a.z * w2.x + a.w * w3.x;
            acc[r][1] += a.x * w0.y + a.y * w1.y + a.z * w2.y + a.w * w3.y;
            acc[r][2] += a.x * w0.z + a.y * w1.z + a.z * w2.z + a.w * w3.z;
            acc[r][3] += a.x * w0.w + a.y * w1.w + a.z * w2.w + a.w * w3.w;
        }
    }
    __syncthreads();   // everyone done READING sA

    // write T = gelu(acc + b1) back into sA
    {
        const float4 bb = *(const float4*)&b1[c0];
        #pragma unroll
        for (int r = 0; r < 8; ++r) {
            float4 o;
            o.x = gelu_fast(acc[r][0] + bb.x);
            o.y = gelu_fast(acc[r][1] + bb.y);
            o.z = gelu_fast(acc[r][2] + bb.z);
            o.w = gelu_fast(acc[r][3] + bb.w);
            *(float4*)&sA[r0 + r][c0] = o;
        }
    }
    __syncthreads();

    // ---- GEMM 2 ----
    #pragma unroll
    for (int r = 0; r < 8; ++r)
        #pragma unroll
        for (int cc = 0; cc < 4; ++cc) acc[r][cc] = 0.0f;

    for (int k = 0; k < D; k += 4) {
        const float4 w0 = *(const float4*)&W2[(size_t)(k + 0) * D + c0];
        const float4 w1 = *(const float4*)&W2[(size_t)(k + 1) * D + c0];
        const float4 w2 = *(const float4*)&W2[(size_t)(k + 2) * D + c0];
        const float4 w3 = *(const float4*)&W2[(size_t)(k + 3) * D + c0];
        #pragma unroll
        for (int r = 0; r < 8; ++r) {
            const float4 a = *(const float4*)&sA[r0 + r][k];
            acc[r][0] += a.x * w0.x + a.y * w1.x + a.z * w2.x + a.w * w3.x;
            acc[r][1] += a.x * w0.y + a.y * w1.y + a.z * w2.y + a.w * w3.y;
            acc[r][2] += a.x * w0.z + a.y * w1.z + a.z * w2.z + a.w * w3.z;
            acc[r][3] += a.x * w0.w + a.y * w1.w + a.z * w2.w + a.w * w3.w;
        }
    }

    const float4 bb = *(const float4*)&b2[c0];
    float s[4] = {0.f, 0.f, 0.f, 0.f};
    float q[4] = {0.f, 0.f, 0.f, 0.f};
    #pragma unroll
    for (int r = 0; r < 8; ++r) {
        const int gr = row0 + r0 + r;
        if (gr < N_NODES) {
            float4 o;
            o.x = acc[r][0] + bb.x; o.y = acc[r][1] + bb.y;
            o.z = acc[r][2] + bb.z; o.w = acc[r][3] + bb.w;
            *(float4*)&H[(size_t)gr * D + c0] = o;
            s[0] += o.x; s[1] += o.y; s[2] += o.z; s[3] += o.w;
            q[0] += o.x * o.x; q[1] += o.y * o.y; q[2] += o.z * o.z; q[3] += o.w * o.w;
        }
    }

    __syncthreads();   // done READING sA in GEMM2
    #pragma unroll
    for (int cc = 0; cc < 4; ++cc) {
        sA[rg][c0 + cc]     = s[cc];
        sA[8 + rg][c0 + cc] = q[cc];
    }
    __syncthreads();
    if (t < D) {
        float ss = 0.f, qq = 0.f;
        #pragma unroll
        for (int gg = 0; gg < 8; ++gg) { ss += sA[gg][t]; qq += sA[8 + gg][t]; }
        atomicAdd(&colsum[t], ss);
        atomicAdd(&colsumsq[t], qq);
    }
}

// ---------------- BN apply + gelu + residual ----------------
__global__ __launch_bounds__(256) void bn_apply_kernel(
    const float* __restrict__ H,
    const float* __restrict__ colsum,
    const float* __restrict__ colsumsq,
    const float* __restrict__ gamma,
    const float* __restrict__ beta,
    const float* __restrict__ x_in,
    float* __restrict__ x_out)
{
    const int idx = blockIdx.x * 256 + threadIdx.x;
    const int c0 = (idx & 31) * 4;
    const float invN = 1.0f / (float)N_NODES;

    const float4 s  = *(const float4*)&colsum[c0];
    const float4 q  = *(const float4*)&colsumsq[c0];
    const float4 g  = *(const float4*)&gamma[c0];
    const float4 bt = *(const float4*)&beta[c0];
    const float4 h  = *(const float4*)&H[(size_t)idx * 4];
    const float4 xv = *(const float4*)&x_in[(size_t)idx * 4];

    float4 o;
    {
        float mu = s.x * invN, var = q.x * invN - mu * mu;
        float hn = (h.x - mu) * rsqrtf(var + BN_EPS) * g.x + bt.x;
        o.x = (xv.x + gelu_fast(hn)) * INV_SQRT2;
    }
    {
        float mu = s.y * invN, var = q.y * invN - mu * mu;
        float hn = (h.y - mu) * rsqrtf(var + BN_EPS) * g.y + bt.y;
        o.y = (xv.y + gelu_fast(hn)) * INV_SQRT2;
    }
    {
        float mu = s.z * invN, var = q.z * invN - mu * mu;
        float hn = (h.z - mu) * rsqrtf(var + BN_EPS) * g.z + bt.z;
        o.z = (xv.z + gelu_fast(hn)) * INV_SQRT2;
    }
    {
        float mu = s.w * invN, var = q.w * invN - mu * mu;
        float hn = (h.w - mu) * rsqrtf(var + BN_EPS) * g.w + bt.w;
        o.w = (xv.w + gelu_fast(hn)) * INV_SQRT2;
    }
    *(float4*)&x_out[(size_t)idx * 4] = o;
}

extern "C" void kernel_launch(void* const* d_in, const int* in_sizes, int n_in,
                              void* d_out, int out_size, void* d_ws, size_t ws_size,
                              hipStream_t stream) {
    const float* x_in  = (const float*)d_in[0];
    const int*   ei    = (const int*)d_in[1];
    const float* ea    = (const float*)d_in[2];
    const float* ew    = (const float*)d_in[3];
    const float* We    = (const float*)d_in[4];
    const float* be    = (const float*)d_in[5];
    const float* W1    = (const float*)d_in[6];
    const float* b1    = (const float*)d_in[7];
    const float* W2    = (const float*)d_in[8];
    const float* b2    = (const float*)d_in[9];
    const float* eps   = (const float*)d_in[10];
    const float* gamma = (const float*)d_in[11];
    const float* beta  = (const float*)d_in[12];

    const int* src = ei;
    const int* dst = ei + N_EDGES;

    float* xcur = (float*)d_out;

    // ws layout (ints unless noted):
    // [counts 50000][colsum_all 384f][colsumsq_all 384f][cursor 50000]
    // [offsets 50004][bsum 256][bbase 256][sorted_eid 800000][preH 6.4Mf]
    int*   counts      = (int*)d_ws;
    float* colsum_all  = (float*)(counts + N_NODES);
    float* colsumsq_all= colsum_all + NLAYERS * D;
    int*   cursor      = (int*)(colsumsq_all + NLAYERS * D);
    int*   offsets     = cursor + N_NODES;
    int*   bsum        = offsets + N_NODES + 4;
    int*   bbase       = bsum + 256;
    int*   sorted_eid  = bbase + 256;
    float* preH        = (float*)(sorted_eid + N_EDGES);  // pre aliased by H

    // zero counts + all per-layer colsums in ONE memset (contiguous)
    hipMemsetAsync(counts, 0, sizeof(int) * (N_NODES + 2 * NLAYERS * D), stream);
    count_kernel<<<(N_EDGES + 255) / 256, 256, 0, stream>>>(dst, counts);
    scan1_kernel<<<NSCAN_BLOCKS, 256, 0, stream>>>(counts, offsets, bsum);
    scan2_kernel<<<1, 256, 0, stream>>>(bsum, bbase, offsets);
    scan3_kernel<<<NSCAN_BLOCKS, 256, 0, stream>>>(offsets, bbase, cursor);
    scatter_kernel<<<(N_EDGES + 255) / 256, 256, 0, stream>>>(dst, cursor, sorted_eid);

    const int mlp_blocks = (N_NODES + GM - 1) / GM;   // 782
    const int bn_blocks  = (N_NODES * D / 4) / 256;   // 6250 exact
    const int agg_blocks = N_NODES / 4;               // 12500 exact

    for (int i = 0; i < NLAYERS; ++i) {
        const float* xl = (i == 0) ? x_in : xcur;
        aggregate_kernel<<<agg_blocks, 256, 0, stream>>>(
            xl, src, ea, ew, offsets, sorted_eid, We, be, eps + i, preH);
        mlp_fused_kernel<<<mlp_blocks, 256, 0, stream>>>(
            preH, W1 + (size_t)i * D * D, b1 + (size_t)i * D,
            W2 + (size_t)i * D * D, b2 + (size_t)i * D,
            preH, colsum_all + i * D, colsumsq_all + i * D);
        bn_apply_kernel<<<bn_blocks, 256, 0, stream>>>(
            preH, colsum_all + i * D, colsumsq_all + i * D,
            gamma + (size_t)i * D, beta + (size_t)i * D, xl, xcur);
    }
}

// Round 4
// 884.628 us; speedup vs baseline: 1.6563x; 1.0479x over previous
//
#include <hip/hip_runtime.h>
#include <math.h>

#define N_NODES 50000
#define N_EDGES 800000
#define D 128
#define E_FEAT 16
#define NLAYERS 3
#define BN_EPS 1e-5f
#define INV_SQRT2 0.70710678118654752f

// Branchless erf (Abramowitz-Stegun 7.1.26, |err| <= 1.5e-7) via hw rcp/exp2.
__device__ __forceinline__ float gelu_fast(float v) {
    const float u = v * INV_SQRT2;
    const float a = __builtin_fabsf(u);
    const float t = __builtin_amdgcn_rcpf(__builtin_fmaf(0.3275911f, a, 1.0f));
    float p = __builtin_fmaf(1.061405429f, t, -1.453152027f);
    p = __builtin_fmaf(p, t, 1.421413741f);
    p = __builtin_fmaf(p, t, -0.284496736f);
    p = __builtin_fmaf(p, t, 0.254829592f);
    p = p * t;
    const float e = __builtin_amdgcn_exp2f(-1.4426950408889634f * a * a);
    const float erf_a = __builtin_fmaf(-p, e, 1.0f);
    const float erf_u = __builtin_copysignf(erf_a, u);
    return 0.5f * v * (1.0f + erf_u);
}

// ---------------- CSR build ----------------
__global__ __launch_bounds__(256) void count_kernel(const int* __restrict__ dst,
                                                    int* __restrict__ counts) {
    int e = blockIdx.x * 256 + threadIdx.x;
    if (e < N_EDGES) atomicAdd(&counts[dst[e]], 1);
}

#define NSCAN_BLOCKS 196
__global__ __launch_bounds__(256) void scan1_kernel(const int* __restrict__ counts,
                                                    int* __restrict__ offsets,
                                                    int* __restrict__ bsum) {
    __shared__ int wsum[4];
    __shared__ int wexcl[4];
    const int t = threadIdx.x, lane = t & 63, wid = t >> 6;
    const int idx = blockIdx.x * 256 + t;
    int v = (idx < N_NODES) ? counts[idx] : 0;
    int incl = v;
    #pragma unroll
    for (int off = 1; off < 64; off <<= 1) {
        int u = __shfl_up(incl, off, 64);
        if (lane >= off) incl += u;
    }
    if (lane == 63) wsum[wid] = incl;
    __syncthreads();
    if (t == 0) {
        int r = 0;
        #pragma unroll
        for (int g = 0; g < 4; ++g) { wexcl[g] = r; r += wsum[g]; }
        bsum[blockIdx.x] = r;
    }
    __syncthreads();
    if (idx < N_NODES) offsets[idx] = wexcl[wid] + (incl - v);
}

__global__ __launch_bounds__(256) void scan2_kernel(const int* __restrict__ bsum,
                                                    int* __restrict__ bbase,
                                                    int* __restrict__ offsets) {
    __shared__ int wsum[4];
    __shared__ int wexcl[4];
    const int t = threadIdx.x, lane = t & 63, wid = t >> 6;
    int v = (t < NSCAN_BLOCKS) ? bsum[t] : 0;
    int incl = v;
    #pragma unroll
    for (int off = 1; off < 64; off <<= 1) {
        int u = __shfl_up(incl, off, 64);
        if (lane >= off) incl += u;
    }
    if (lane == 63) wsum[wid] = incl;
    __syncthreads();
    if (t == 0) {
        int r = 0;
        #pragma unroll
        for (int g = 0; g < 4; ++g) { wexcl[g] = r; r += wsum[g]; }
        offsets[N_NODES] = r;
    }
    __syncthreads();
    if (t < NSCAN_BLOCKS) bbase[t] = wexcl[wid] + (incl - v);
}

__global__ __launch_bounds__(256) void scan3_kernel(int* __restrict__ offsets,
                                                    const int* __restrict__ bbase,
                                                    int* __restrict__ cursor) {
    const int idx = blockIdx.x * 256 + threadIdx.x;
    if (idx < N_NODES) {
        const int o = offsets[idx] + bbase[blockIdx.x];
        offsets[idx] = o;
        cursor[idx] = o;
    }
}

// scatter: permute ALL per-edge metadata into dst-sorted order so the
// aggregate loop reads only affine uniform addresses (scalar-prefetchable).
__global__ __launch_bounds__(256) void scatter_kernel(
    const int* __restrict__ dst,
    const int* __restrict__ src,
    const float* __restrict__ ew,
    const float* __restrict__ ea,
    int* __restrict__ cursor,
    int* __restrict__ sorted_src,
    float* __restrict__ sorted_ew,
    float* __restrict__ sorted_ea)
{
    int e = blockIdx.x * 256 + threadIdx.x;
    if (e < N_EDGES) {
        int p = atomicAdd(&cursor[dst[e]], 1);
        sorted_src[p] = src[e];
        sorted_ew[p]  = ew[e];
        const float4* s4 = (const float4*)(ea + (size_t)e * E_FEAT);
        float4* d4 = (float4*)(sorted_ea + (size_t)p * E_FEAT);
        d4[0] = s4[0]; d4[1] = s4[1]; d4[2] = s4[2]; d4[3] = s4[3];
    }
}

// ---------------- aggregation: one wave per dst node ----------------
// pre[n] = (1+eps)*x[n] + sum_{e: dst=n} gelu(x[src_e] + ea_e@We + be) * ew_e
__global__ __launch_bounds__(256) void aggregate_kernel(
    const float* __restrict__ x,
    const int* __restrict__ sorted_src,
    const float* __restrict__ sorted_ew,
    const float* __restrict__ sorted_ea,
    const int* __restrict__ offsets,
    const float* __restrict__ We,          // 16 x 128
    const float* __restrict__ be,          // 128
    const float* __restrict__ eps_p,
    float* __restrict__ pre)               // N x 128
{
    const int t = threadIdx.x;
    const int lane = t & 63;
    const int node = blockIdx.x * 4 + (t >> 6);
    const int c0 = lane * 2;

    float2 wreg[E_FEAT];
    #pragma unroll
    for (int k = 0; k < E_FEAT; ++k)
        wreg[k] = *(const float2*)&We[k * D + c0];
    const float2 bev = *(const float2*)&be[c0];
    const float e1 = 1.0f + *eps_p;

    const int start = __builtin_amdgcn_readfirstlane(offsets[node]);
    const int end   = __builtin_amdgcn_readfirstlane(offsets[node + 1]);

    float a0 = 0.0f, a1 = 0.0f;
    float2 xv = {0.0f, 0.0f};
    if (start < end) {
        const int s0 = sorted_src[start];               // uniform scalar load
        xv = *(const float2*)&x[(size_t)s0 * D + c0];   // sgpr base + lane offset
    }
    for (int p = start; p < end; ++p) {
        const float w = sorted_ew[p];                   // uniform affine -> s_load
        const float* __restrict__ ear = sorted_ea + (size_t)p * E_FEAT;
        float m0 = bev.x, m1 = bev.y;
        #pragma unroll
        for (int k = 0; k < E_FEAT; ++k) {
            const float eak = ear[k];                   // uniform affine -> s_load
            m0 = __builtin_fmaf(eak, wreg[k].x, m0);
            m1 = __builtin_fmaf(eak, wreg[k].y, m1);
        }
        const float2 xc = xv;
        if (p + 1 < end) {
            const int sn = sorted_src[p + 1];           // prefetch next gather
            xv = *(const float2*)&x[(size_t)sn * D + c0];
        }
        a0 = __builtin_fmaf(gelu_fast(xc.x + m0), w, a0);
        a1 = __builtin_fmaf(gelu_fast(xc.y + m1), w, a1);
    }
    const float2 xn = *(const float2*)&x[(size_t)node * D + c0];
    float2 o;
    o.x = e1 * xn.x + a0;
    o.y = e1 * xn.y + a1;
    *(float2*)&pre[(size_t)node * D + c0] = o;
}

// ---------------- fused MLP: H = gelu(pre@W1+b1)@W2+b2, plus col stats ----------------
#define GM 64
#define LDA 132

__global__ __launch_bounds__(256) void mlp_fused_kernel(
    const float* __restrict__ pre,
    const float* __restrict__ W1,
    const float* __restrict__ b1,
    const float* __restrict__ W2,
    const float* __restrict__ b2,
    float* __restrict__ H,
    float* __restrict__ colsum,
    float* __restrict__ colsumsq)
{
    __shared__ float sA[GM][LDA];
    const int t = threadIdx.x;
    const int row0 = blockIdx.x * GM;

    for (int i = t; i < GM * (D / 4); i += 256) {
        const int r  = i / (D / 4);
        const int cc = (i % (D / 4)) * 4;
        const int gr = row0 + r;
        float4 v;
        if (gr < N_NODES) v = *(const float4*)&pre[(size_t)gr * D + cc];
        else { v.x = v.y = v.z = v.w = 0.0f; }
        *(float4*)&sA[r][cc] = v;
    }
    __syncthreads();

    const int cg = t & 31;
    const int rg = t >> 5;
    const int c0 = cg * 4;
    const int r0 = rg * 8;
    float acc[8][4];

    #pragma unroll
    for (int r = 0; r < 8; ++r)
        #pragma unroll
        for (int cc = 0; cc < 4; ++cc) acc[r][cc] = 0.0f;

    for (int k = 0; k < D; k += 4) {
        const float4 w0 = *(const float4*)&W1[(size_t)(k + 0) * D + c0];
        const float4 w1 = *(const float4*)&W1[(size_t)(k + 1) * D + c0];
        const float4 w2 = *(const float4*)&W1[(size_t)(k + 2) * D + c0];
        const float4 w3 = *(const float4*)&W1[(size_t)(k + 3) * D + c0];
        #pragma unroll
        for (int r = 0; r < 8; ++r) {
            const float4 a = *(const float4*)&sA[r0 + r][k];
            acc[r][0] += a.x * w0.x + a.y * w1.x + a.z * w2.x + a.w * w3.x;
            acc[r][1] += a.x * w0.y + a.y * w1.y + a.z * w2.y + a.w * w3.y;
            acc[r][2] += a.x * w0.z + a.y * w1.z + a.z * w2.z + a.w * w3.z;
            acc[r][3] += a.x * w0.w + a.y * w1.w + a.z * w2.w + a.w * w3.w;
        }
    }
    __syncthreads();

    {
        const float4 bb = *(const float4*)&b1[c0];
        #pragma unroll
        for (int r = 0; r < 8; ++r) {
            float4 o;
            o.x = gelu_fast(acc[r][0] + bb.x);
            o.y = gelu_fast(acc[r][1] + bb.y);
            o.z = gelu_fast(acc[r][2] + bb.z);
            o.w = gelu_fast(acc[r][3] + bb.w);
            *(float4*)&sA[r0 + r][c0] = o;
        }
    }
    __syncthreads();

    #pragma unroll
    for (int r = 0; r < 8; ++r)
        #pragma unroll
        for (int cc = 0; cc < 4; ++cc) acc[r][cc] = 0.0f;

    for (int k = 0; k < D; k += 4) {
        const float4 w0 = *(const float4*)&W2[(size_t)(k + 0) * D + c0];
        const float4 w1 = *(const float4*)&W2[(size_t)(k + 1) * D + c0];
        const float4 w2 = *(const float4*)&W2[(size_t)(k + 2) * D + c0];
        const float4 w3 = *(const float4*)&W2[(size_t)(k + 3) * D + c0];
        #pragma unroll
        for (int r = 0; r < 8; ++r) {
            const float4 a = *(const float4*)&sA[r0 + r][k];
            acc[r][0] += a.x * w0.x + a.y * w1.x + a.z * w2.x + a.w * w3.x;
            acc[r][1] += a.x * w0.y + a.y * w1.y + a.z * w2.y + a.w * w3.y;
            acc[r][2] += a.x * w0.z + a.y * w1.z + a.z * w2.z + a.w * w3.z;
            acc[r][3] += a.x * w0.w + a.y * w1.w + a.z * w2.w + a.w * w3.w;
        }
    }

    const float4 bb = *(const float4*)&b2[c0];
    float s[4] = {0.f, 0.f, 0.f, 0.f};
    float q[4] = {0.f, 0.f, 0.f, 0.f};
    #pragma unroll
    for (int r = 0; r < 8; ++r) {
        const int gr = row0 + r0 + r;
        if (gr < N_NODES) {
            float4 o;
            o.x = acc[r][0] + bb.x; o.y = acc[r][1] + bb.y;
            o.z = acc[r][2] + bb.z; o.w = acc[r][3] + bb.w;
            *(float4*)&H[(size_t)gr * D + c0] = o;
            s[0] += o.x; s[1] += o.y; s[2] += o.z; s[3] += o.w;
            q[0] += o.x * o.x; q[1] += o.y * o.y; q[2] += o.z * o.z; q[3] += o.w * o.w;
        }
    }

    __syncthreads();
    #pragma unroll
    for (int cc = 0; cc < 4; ++cc) {
        sA[rg][c0 + cc]     = s[cc];
        sA[8 + rg][c0 + cc] = q[cc];
    }
    __syncthreads();
    if (t < D) {
        float ss = 0.f, qq = 0.f;
        #pragma unroll
        for (int gg = 0; gg < 8; ++gg) { ss += sA[gg][t]; qq += sA[8 + gg][t]; }
        atomicAdd(&colsum[t], ss);
        atomicAdd(&colsumsq[t], qq);
    }
}

// ---------------- BN apply + gelu + residual ----------------
__global__ __launch_bounds__(256) void bn_apply_kernel(
    const float* __restrict__ H,
    const float* __restrict__ colsum,
    const float* __restrict__ colsumsq,
    const float* __restrict__ gamma,
    const float* __restrict__ beta,
    const float* __restrict__ x_in,
    float* __restrict__ x_out)
{
    const int idx = blockIdx.x * 256 + threadIdx.x;
    const int c0 = (idx & 31) * 4;
    const float invN = 1.0f / (float)N_NODES;

    const float4 s  = *(const float4*)&colsum[c0];
    const float4 q  = *(const float4*)&colsumsq[c0];
    const float4 g  = *(const float4*)&gamma[c0];
    const float4 bt = *(const float4*)&beta[c0];
    const float4 h  = *(const float4*)&H[(size_t)idx * 4];
    const float4 xv = *(const float4*)&x_in[(size_t)idx * 4];

    float4 o;
    {
        float mu = s.x * invN, var = q.x * invN - mu * mu;
        float hn = (h.x - mu) * rsqrtf(var + BN_EPS) * g.x + bt.x;
        o.x = (xv.x + gelu_fast(hn)) * INV_SQRT2;
    }
    {
        float mu = s.y * invN, var = q.y * invN - mu * mu;
        float hn = (h.y - mu) * rsqrtf(var + BN_EPS) * g.y + bt.y;
        o.y = (xv.y + gelu_fast(hn)) * INV_SQRT2;
    }
    {
        float mu = s.z * invN, var = q.z * invN - mu * mu;
        float hn = (h.z - mu) * rsqrtf(var + BN_EPS) * g.z + bt.z;
        o.z = (xv.z + gelu_fast(hn)) * INV_SQRT2;
    }
    {
        float mu = s.w * invN, var = q.w * invN - mu * mu;
        float hn = (h.w - mu) * rsqrtf(var + BN_EPS) * g.w + bt.w;
        o.w = (xv.w + gelu_fast(hn)) * INV_SQRT2;
    }
    *(float4*)&x_out[(size_t)idx * 4] = o;
}

extern "C" void kernel_launch(void* const* d_in, const int* in_sizes, int n_in,
                              void* d_out, int out_size, void* d_ws, size_t ws_size,
                              hipStream_t stream) {
    const float* x_in  = (const float*)d_in[0];
    const int*   ei    = (const int*)d_in[1];
    const float* ea    = (const float*)d_in[2];
    const float* ew    = (const float*)d_in[3];
    const float* We    = (const float*)d_in[4];
    const float* be    = (const float*)d_in[5];
    const float* W1    = (const float*)d_in[6];
    const float* b1    = (const float*)d_in[7];
    const float* W2    = (const float*)d_in[8];
    const float* b2    = (const float*)d_in[9];
    const float* eps   = (const float*)d_in[10];
    const float* gamma = (const float*)d_in[11];
    const float* beta  = (const float*)d_in[12];

    const int* src = ei;
    const int* dst = ei + N_EDGES;

    float* xcur = (float*)d_out;

    // ws layout:
    // [counts 50000][colsum_all 384f][colsumsq_all 384f][cursor 50000]
    // [offsets 50004][bsum 256][bbase 256][sorted_src 800000][sorted_ew 800000f]
    // [sorted_ea 12.8Mf (16B-aligned)][preH 6.4Mf]
    int*   counts       = (int*)d_ws;
    float* colsum_all   = (float*)(counts + N_NODES);
    float* colsumsq_all = colsum_all + NLAYERS * D;
    int*   cursor       = (int*)(colsumsq_all + NLAYERS * D);
    int*   offsets      = cursor + N_NODES;
    int*   bsum         = offsets + N_NODES + 4;
    int*   bbase        = bsum + 256;
    int*   sorted_src   = bbase + 256;
    float* sorted_ew    = (float*)(sorted_src + N_EDGES);
    float* sorted_ea    = sorted_ew + N_EDGES;     // 16B-aligned by construction
    float* preH         = sorted_ea + (size_t)N_EDGES * E_FEAT;

    hipMemsetAsync(counts, 0, sizeof(int) * (N_NODES + 2 * NLAYERS * D), stream);
    count_kernel<<<(N_EDGES + 255) / 256, 256, 0, stream>>>(dst, counts);
    scan1_kernel<<<NSCAN_BLOCKS, 256, 0, stream>>>(counts, offsets, bsum);
    scan2_kernel<<<1, 256, 0, stream>>>(bsum, bbase, offsets);
    scan3_kernel<<<NSCAN_BLOCKS, 256, 0, stream>>>(offsets, bbase, cursor);
    scatter_kernel<<<(N_EDGES + 255) / 256, 256, 0, stream>>>(
        dst, src, ew, ea, cursor, sorted_src, sorted_ew, sorted_ea);

    const int mlp_blocks = (N_NODES + GM - 1) / GM;
    const int bn_blocks  = (N_NODES * D / 4) / 256;
    const int agg_blocks = N_NODES / 4;

    for (int i = 0; i < NLAYERS; ++i) {
        const float* xl = (i == 0) ? x_in : xcur;
        aggregate_kernel<<<agg_blocks, 256, 0, stream>>>(
            xl, sorted_src, sorted_ew, sorted_ea, offsets, We, be, eps + i, preH);
        mlp_fused_kernel<<<mlp_blocks, 256, 0, stream>>>(
            preH, W1 + (size_t)i * D * D, b1 + (size_t)i * D,
            W2 + (size_t)i * D * D, b2 + (size_t)i * D,
            preH, colsum_all + i * D, colsumsq_all + i * D);
        bn_apply_kernel<<<bn_blocks, 256, 0, stream>>>(
            preH, colsum_all + i * D, colsumsq_all + i * D,
            gamma + (size_t)i * D, beta + (size_t)i * D, xl, xcur);
    }
}